// Round 13
// baseline (5029.567 us; speedup 1.0000x reference)
//
#include <hip/hip_runtime.h>
#include <cstdint>
#include <cstddef>

#define NB 32
#define NT 2048
#define ND 256
#define NH 256
#define NG 1024   // 4*H

#define TPB 512             // rec: 8 waves = 2/EU, 1 block/CU (LDS-forced)
#define KL  48              // k-values with weights in LDS (6 uint4 rows = 96 KB)
#define NQ  ((ND - KL) / 2) // 104 f16 packs per column in regs (x2 cols)

typedef _Float16 h2_t  __attribute__((ext_vector_type(2)));
typedef _Float16 f16x8 __attribute__((ext_vector_type(8)));
typedef float    f32x4 __attribute__((ext_vector_type(4)));

__device__ __forceinline__ float sigf(float x) {
    return 1.0f / (1.0f + __expf(-x));
}
__device__ __forceinline__ float tanh_fast(float x) {
    return 2.0f / (1.0f + __expf(-2.0f * x)) - 1.0f;
}

__device__ __forceinline__ h2_t as_h2(uint32_t u) {
    union { uint32_t u; h2_t h; } c; c.u = u; return c.h;
}
__device__ __forceinline__ uint32_t packf16(float a, float b) {
    union { uint32_t u; h2_t h; } c;
    c.h[0] = (_Float16)a; c.h[1] = (_Float16)b;
    return c.u;
}
__device__ __forceinline__ float dot2(uint32_t hpack, uint32_t wpack, float acc) {
    return __builtin_amdgcn_fdot2(as_h2(hpack), as_h2(wpack), acc, false);
}

// ---------------------------------------------------------------------------
// Phase 1: ZX[bt][j] = sum_k X[bt][k] * Wi[k][j] + bias[j]  via f16 MFMA.
// (unchanged from R12: ~130 us measured)
__global__ __launch_bounds__(256) void zx_mfma(const float* __restrict__ X,
                                               const float* __restrict__ Wi,
                                               const float* __restrict__ bias,
                                               float* __restrict__ ZX)
{
    __shared__ _Float16 XL[64][264];               // 33.8 KB (pad 8 -> 2-way free)

    const int t    = threadIdx.x;
    const int mblk = blockIdx.x;
    const int nblk = blockIdx.y;
    const size_t row0 = (size_t)mblk * 64;
    const int n0   = nblk * 256;
    const int l    = t & 63;
    const int w    = t >> 6;
    const int cc   = l & 15;                       // A-row / B-col / D-col class
    const int g    = l >> 4;                       // k-group / D-row class
    const int wm   = (w & 1) * 32;                 // wave M offset
    const int wn   = (w >> 1) * 128;               // wave N offset

    // ---- stage X tile: 64 rows x 256 f32 -> f16 (coalesced float4) ----
    const float4* Xv = (const float4*)(X + row0 * ND);
#pragma unroll
    for (int i = 0; i < 16; ++i) {
        const int q   = i * 256 + t;               // float4 index in tile
        const int row = q >> 6;
        const int c4  = q & 63;
        const float4 v = Xv[q];
        _Float16* dst = &XL[row][c4 * 4];
        dst[0] = (_Float16)v.x; dst[1] = (_Float16)v.y;
        dst[2] = (_Float16)v.z; dst[3] = (_Float16)v.w;
    }
    __syncthreads();

    // ---- accumulators, bias in C operand (D col = cc for all 4 regs) ----
    f32x4 acc[2][8];
#pragma unroll
    for (int nt = 0; nt < 8; ++nt) {
        const float bv = bias[n0 + wn + nt * 16 + cc];
        f32x4 a; a[0] = bv; a[1] = bv; a[2] = bv; a[3] = bv;
        acc[0][nt] = a; acc[1][nt] = a;
    }

#pragma unroll
    for (int kt = 0; kt < 8; ++kt) {
        const f16x8 av0 = *(const f16x8*)&XL[wm +      cc][kt * 32 + 8 * g];
        const f16x8 av1 = *(const f16x8*)&XL[wm + 16 + cc][kt * 32 + 8 * g];
#pragma unroll
        for (int nt = 0; nt < 8; ++nt) {
            const float* wp = Wi + (size_t)(kt * 32 + 8 * g) * NG
                              + n0 + wn + nt * 16 + cc;
            f16x8 bv;
#pragma unroll
            for (int j = 0; j < 8; ++j) bv[j] = (_Float16)wp[(size_t)j * NG];
            acc[0][nt] = __builtin_amdgcn_mfma_f32_16x16x32_f16(av0, bv, acc[0][nt], 0, 0, 0);
            acc[1][nt] = __builtin_amdgcn_mfma_f32_16x16x32_f16(av1, bv, acc[1][nt], 0, 0, 0);
        }
    }

    // ---- write out: D row = 4*g + r, col = cc ----
#pragma unroll
    for (int m = 0; m < 2; ++m)
#pragma unroll
        for (int nt = 0; nt < 8; ++nt)
#pragma unroll
            for (int r = 0; r < 4; ++r) {
                const size_t row = row0 + wm + 16 * m + 4 * g + r;
                ZX[row * NG + n0 + wn + nt * 16 + cc] = acc[m][nt][r];
            }
}

// ---------------------------------------------------------------------------
// Phase 2: persistent-weight recurrence (R8 structure; KL 64->48).
// One block per batch, 512 threads (8 waves = 2/EU). Thread tid owns gate
// columns {tid, tid+512}. Wh packed f16: k=0..KL-1 in LDS (96 KB);
// k=KL..255 as 2x104 packs pinned via opaque asm (no remat -> no spill).
// Demand = 208 packs + ~25 working = 233 of the 256-reg 2/EU budget --
// 16 past R8's proven 217. WRITE_SIZE is the spill tell: <=1 MB ok,
// >5 MB means the residency cliff was crossed (then revert KL=64).
__global__
__attribute__((amdgpu_flat_work_group_size(TPB, TPB)))
__attribute__((amdgpu_waves_per_eu(2, 2)))
void rec_pers(const float* __restrict__ ZX,
              const float* __restrict__ Wh,
              const int* __restrict__ lengths,
              float* __restrict__ out)
{
    __shared__ uint4 lw[KL / 8][NG];               // 96 KB
    __shared__ float zs[NG];                       // 4 KB
    __shared__ __align__(16) _Float16 hs_h[NH];    // 512 B

    const int b   = blockIdx.x;
    const int tid = threadIdx.x;
    const int j0  = tid;
    const int j1  = tid + 512;

    // ---- one-time LDS staging (coalesced over j at fixed k) ----
#pragma unroll
    for (int r = 0; r < KL / 8; ++r) {
        const int k = 8 * r;
        uint4 p;
        p.x = packf16(Wh[(size_t)(k + 0) * NG + j0], Wh[(size_t)(k + 1) * NG + j0]);
        p.y = packf16(Wh[(size_t)(k + 2) * NG + j0], Wh[(size_t)(k + 3) * NG + j0]);
        p.z = packf16(Wh[(size_t)(k + 4) * NG + j0], Wh[(size_t)(k + 5) * NG + j0]);
        p.w = packf16(Wh[(size_t)(k + 6) * NG + j0], Wh[(size_t)(k + 7) * NG + j0]);
        lw[r][j0] = p;
        p.x = packf16(Wh[(size_t)(k + 0) * NG + j1], Wh[(size_t)(k + 1) * NG + j1]);
        p.y = packf16(Wh[(size_t)(k + 2) * NG + j1], Wh[(size_t)(k + 3) * NG + j1]);
        p.z = packf16(Wh[(size_t)(k + 4) * NG + j1], Wh[(size_t)(k + 5) * NG + j1]);
        p.w = packf16(Wh[(size_t)(k + 6) * NG + j1], Wh[(size_t)(k + 7) * NG + j1]);
        lw[r][j1] = p;
    }

    // ---- register-resident weights, pinned against remat ----
    uint32_t wa[NQ], wb[NQ];
#pragma unroll
    for (int q = 0; q < NQ; ++q) {
        const int k = KL + 2 * q;
        uint32_t va = packf16(Wh[(size_t)k * NG + j0], Wh[(size_t)(k + 1) * NG + j0]);
        uint32_t vb = packf16(Wh[(size_t)k * NG + j1], Wh[(size_t)(k + 1) * NG + j1]);
        asm volatile("" : "+v"(va));               // opaque def: no remat
        asm volatile("" : "+v"(vb));
        wa[q] = va;
        wb[q] = vb;
    }

    if (tid < NH) hs_h[tid] = (_Float16)0.0f;
    float c = 0.0f, hlast = 0.0f;
    __syncthreads();

    const int len   = lengths[b];
    const int steps = (len < 1) ? 1 : len;         // idx = max(0,len-1) -> idx+1 steps

    for (int t = 0; t < steps; ++t) {
        // issue early; consumed only at zs write (dot work hides L3/HBM latency)
        const float zx0 = ZX[((size_t)b * NT + t) * NG + j0];
        const float zx1 = ZX[((size_t)b * NT + t) * NG + j1];

        float a0 = 0.0f, a1 = 0.0f;    // col j0
        float b0 = 0.0f, b1 = 0.0f;    // col j1

        // k = 0..KL-1: weights from LDS (16B lane stride = free 2-way)
#pragma unroll
        for (int r = 0; r < KL / 8; ++r) {
            const uint4 h4 = *(const uint4*)(hs_h + 8 * r);   // broadcast
            const uint4 pa = lw[r][j0];
            const uint4 pb = lw[r][j1];
            a0 = dot2(h4.x, pa.x, a0); a1 = dot2(h4.y, pa.y, a1);
            a0 = dot2(h4.z, pa.z, a0); a1 = dot2(h4.w, pa.w, a1);
            b0 = dot2(h4.x, pb.x, b0); b1 = dot2(h4.y, pb.y, b1);
            b0 = dot2(h4.z, pb.z, b0); b1 = dot2(h4.w, pb.w, b1);
        }

        // k = KL..255: register-resident weights
#pragma unroll
        for (int m = 0; m < NQ / 4; ++m) {
            const uint4 h4 = *(const uint4*)(hs_h + KL + 8 * m);  // broadcast
            a0 = dot2(h4.x, wa[4 * m + 0], a0);
            a1 = dot2(h4.y, wa[4 * m + 1], a1);
            a0 = dot2(h4.z, wa[4 * m + 2], a0);
            a1 = dot2(h4.w, wa[4 * m + 3], a1);
            b0 = dot2(h4.x, wb[4 * m + 0], b0);
            b1 = dot2(h4.y, wb[4 * m + 1], b1);
            b0 = dot2(h4.z, wb[4 * m + 2], b0);
            b1 = dot2(h4.w, wb[4 * m + 3], b1);
        }

        zs[j0] = zx0 + a0 + a1;
        zs[j1] = zx1 + b0 + b1;
        __syncthreads();                            // zs complete

        if (tid < NH) {                             // waves 0-3 (wave-uniform)
            const float iv = zs[tid];
            const float fv = zs[NH + tid];
            const float gv = zs[2 * NH + tid];
            const float ov = zs[3 * NH + tid];
            c = sigf(fv) * c + sigf(iv) * tanh_fast(gv);
            hlast = sigf(ov) * tanh_fast(c);
            hs_h[tid] = (_Float16)hlast;
        }
        __syncthreads();                            // new h visible
    }

    if (tid < NH) out[(size_t)b * NH + tid] = hlast;
}

// ---------------------------------------------------------------------------
// Fallback recurrence (streams weights; used only if ws can't hold ZX)
__global__ __launch_bounds__(512) void rec_fallback(
    const float* __restrict__ X,
    const float* __restrict__ Wi,
    const float* __restrict__ Wh,
    const float* __restrict__ bias,
    const int* __restrict__ lengths,
    float* __restrict__ out)
{
    __shared__ float hs[NH];
    __shared__ float zs[NG];
    __shared__ float xs[ND];

    const int b   = blockIdx.x;
    const int tid = threadIdx.x;
    const int c0  = tid * 2;

    const int len   = lengths[b];
    const int steps = (len < 1) ? 1 : len;

    float c_state = 0.0f;
    if (tid < NH) hs[tid] = 0.0f;
    const float b0 = bias[c0], b1 = bias[c0 + 1];
    __syncthreads();

    for (int t = 0; t < steps; ++t) {
        float a0 = b0, a1 = b1;
        if (tid < ND) xs[tid] = X[((size_t)b * NT + t) * ND + tid];
        __syncthreads();
#pragma unroll 2
        for (int k = 0; k < ND; k += 4) {
            const float4 xv = *(const float4*)(xs + k);
            const float2 w0 = *(const float2*)(Wi + (size_t)(k + 0) * NG + c0);
            const float2 w1 = *(const float2*)(Wi + (size_t)(k + 1) * NG + c0);
            const float2 w2 = *(const float2*)(Wi + (size_t)(k + 2) * NG + c0);
            const float2 w3 = *(const float2*)(Wi + (size_t)(k + 3) * NG + c0);
            a0 = fmaf(xv.x, w0.x, a0); a1 = fmaf(xv.x, w0.y, a1);
            a0 = fmaf(xv.y, w1.x, a0); a1 = fmaf(xv.y, w1.y, a1);
            a0 = fmaf(xv.z, w2.x, a0); a1 = fmaf(xv.z, w2.y, a1);
            a0 = fmaf(xv.w, w3.x, a0); a1 = fmaf(xv.w, w3.y, a1);
        }
#pragma unroll 2
        for (int k = 0; k < NH; k += 4) {
            const float4 hv = *(const float4*)(hs + k);
            const float2 w0 = *(const float2*)(Wh + (size_t)(k + 0) * NG + c0);
            const float2 w1 = *(const float2*)(Wh + (size_t)(k + 1) * NG + c0);
            const float2 w2 = *(const float2*)(Wh + (size_t)(k + 2) * NG + c0);
            const float2 w3 = *(const float2*)(Wh + (size_t)(k + 3) * NG + c0);
            a0 = fmaf(hv.x, w0.x, a0); a1 = fmaf(hv.x, w0.y, a1);
            a0 = fmaf(hv.y, w1.x, a0); a1 = fmaf(hv.y, w1.y, a1);
            a0 = fmaf(hv.z, w2.x, a0); a1 = fmaf(hv.z, w2.y, a1);
            a0 = fmaf(hv.w, w3.x, a0); a1 = fmaf(hv.w, w3.y, a1);
        }

        float2 zo2; zo2.x = a0; zo2.y = a1;
        *(float2*)(zs + c0) = zo2;
        __syncthreads();

        if (tid < NH) {
            const float iv = zs[tid];
            const float fv = zs[NH + tid];
            const float gv = zs[2 * NH + tid];
            const float ov = zs[3 * NH + tid];
            c_state = sigf(fv) * c_state + sigf(iv) * tanh_fast(gv);
            hs[tid] = sigf(ov) * tanh_fast(c_state);
        }
        __syncthreads();
    }

    if (tid < NH) out[(size_t)b * NH + tid] = hs[tid];
}

extern "C" void kernel_launch(void* const* d_in, const int* in_sizes, int n_in,
                              void* d_out, int out_size, void* d_ws, size_t ws_size,
                              hipStream_t stream) {
    const float* X       = (const float*)d_in[0];
    const int*   lengths = (const int*)d_in[1];
    const float* Wi      = (const float*)d_in[2];
    const float* Wh      = (const float*)d_in[3];
    const float* bias    = (const float*)d_in[4];
    float* out = (float*)d_out;

    const size_t zx_bytes = (size_t)NB * NT * NG * sizeof(float);  // 256 MB
    float* ZX = (float*)d_ws;

    if (ws_size >= zx_bytes) {
        zx_mfma<<<dim3((NB * NT) / 64, NG / 256), dim3(256), 0, stream>>>(X, Wi, bias, ZX);
        rec_pers<<<dim3(NB), dim3(TPB), 0, stream>>>(ZX, Wh, lengths, out);
    } else {
        rec_fallback<<<dim3(NB), dim3(512), 0, stream>>>(X, Wi, Wh, bias, lengths, out);
    }
}

// Round 14
// 3124.622 us; speedup vs baseline: 1.6097x; 1.6097x over previous
//
#include <hip/hip_runtime.h>
#include <cstdint>
#include <cstddef>

#define NB 32
#define NT 2048
#define ND 256
#define NH 256
#define NG 1024   // 4*H

#define TPB 512             // rec: 8 waves = 2/EU, 1 block/CU (LDS-forced)
#define KL  64              // k-values with weights in LDS (8 uint4 rows = 128 KB)
#define NQ  ((ND - KL) / 2) // 96 f16 packs per column in regs (x2 cols)

typedef _Float16 h2_t  __attribute__((ext_vector_type(2)));
typedef _Float16 f16x8 __attribute__((ext_vector_type(8)));
typedef float    f32x4 __attribute__((ext_vector_type(4)));

__device__ __forceinline__ float sigf(float x) {
    return 1.0f / (1.0f + __expf(-x));
}
__device__ __forceinline__ float tanh_fast(float x) {
    return 2.0f / (1.0f + __expf(-2.0f * x)) - 1.0f;
}

__device__ __forceinline__ h2_t as_h2(uint32_t u) {
    union { uint32_t u; h2_t h; } c; c.u = u; return c.h;
}
__device__ __forceinline__ uint32_t packf16(float a, float b) {
    union { uint32_t u; h2_t h; } c;
    c.h[0] = (_Float16)a; c.h[1] = (_Float16)b;
    return c.u;
}
__device__ __forceinline__ float dot2(uint32_t hpack, uint32_t wpack, float acc) {
    return __builtin_amdgcn_fdot2(as_h2(hpack), as_h2(wpack), acc, false);
}

// ---------------------------------------------------------------------------
// Phase 1: ZX[bt][j] = sum_k X[bt][k] * Wi[k][j] + bias[j]  via f16 MFMA.
// (R12 measured: ~130 us)
__global__ __launch_bounds__(256) void zx_mfma(const float* __restrict__ X,
                                               const float* __restrict__ Wi,
                                               const float* __restrict__ bias,
                                               float* __restrict__ ZX)
{
    __shared__ _Float16 XL[64][264];               // 33.8 KB (pad 8 -> 2-way free)

    const int t    = threadIdx.x;
    const int mblk = blockIdx.x;
    const int nblk = blockIdx.y;
    const size_t row0 = (size_t)mblk * 64;
    const int n0   = nblk * 256;
    const int l    = t & 63;
    const int w    = t >> 6;
    const int cc   = l & 15;                       // A-row / B-col / D-col class
    const int g    = l >> 4;                       // k-group / D-row class
    const int wm   = (w & 1) * 32;                 // wave M offset
    const int wn   = (w >> 1) * 128;               // wave N offset

    // ---- stage X tile: 64 rows x 256 f32 -> f16 (coalesced float4) ----
    const float4* Xv = (const float4*)(X + row0 * ND);
#pragma unroll
    for (int i = 0; i < 16; ++i) {
        const int q   = i * 256 + t;               // float4 index in tile
        const int row = q >> 6;
        const int c4  = q & 63;
        const float4 v = Xv[q];
        _Float16* dst = &XL[row][c4 * 4];
        dst[0] = (_Float16)v.x; dst[1] = (_Float16)v.y;
        dst[2] = (_Float16)v.z; dst[3] = (_Float16)v.w;
    }
    __syncthreads();

    // ---- accumulators, bias in C operand (D col = cc for all 4 regs) ----
    f32x4 acc[2][8];
#pragma unroll
    for (int nt = 0; nt < 8; ++nt) {
        const float bv = bias[n0 + wn + nt * 16 + cc];
        f32x4 a; a[0] = bv; a[1] = bv; a[2] = bv; a[3] = bv;
        acc[0][nt] = a; acc[1][nt] = a;
    }

#pragma unroll
    for (int kt = 0; kt < 8; ++kt) {
        const f16x8 av0 = *(const f16x8*)&XL[wm +      cc][kt * 32 + 8 * g];
        const f16x8 av1 = *(const f16x8*)&XL[wm + 16 + cc][kt * 32 + 8 * g];
#pragma unroll
        for (int nt = 0; nt < 8; ++nt) {
            const float* wp = Wi + (size_t)(kt * 32 + 8 * g) * NG
                              + n0 + wn + nt * 16 + cc;
            f16x8 bv;
#pragma unroll
            for (int j = 0; j < 8; ++j) bv[j] = (_Float16)wp[(size_t)j * NG];
            acc[0][nt] = __builtin_amdgcn_mfma_f32_16x16x32_f16(av0, bv, acc[0][nt], 0, 0, 0);
            acc[1][nt] = __builtin_amdgcn_mfma_f32_16x16x32_f16(av1, bv, acc[1][nt], 0, 0, 0);
        }
    }

    // ---- write out: D row = 4*g + r, col = cc ----
#pragma unroll
    for (int m = 0; m < 2; ++m)
#pragma unroll
        for (int nt = 0; nt < 8; ++nt)
#pragma unroll
            for (int r = 0; r < 4; ++r) {
                const size_t row = row0 + wm + 16 * m + 4 * g + r;
                ZX[row * NG + n0 + wn + nt * 16 + cc] = acc[m][nt][r];
            }
}

// ---------------------------------------------------------------------------
// Phase 2: persistent-weight recurrence (R8/R12 proven local optimum:
// 1.45 us/step). One block per batch, 512 threads (8 waves = 2/EU).
// Thread tid owns gate columns {tid, tid+512}. Wh packed f16:
// k=0..63 in LDS (128 KB); k=64..255 as 2x96 packs pinned via opaque asm.
// Probed neighbors ALL worse: KL=48 (AGPR-read chains, 1.7x), 256thr/1-wave
// (no latency hiding, 2.8x), 4-col gate-local (spill, 6x), 2-CU split
// (exchange latency, 1.6x). Do not perturb without new evidence.
__global__
__attribute__((amdgpu_flat_work_group_size(TPB, TPB)))
__attribute__((amdgpu_waves_per_eu(2, 2)))
void rec_pers(const float* __restrict__ ZX,
              const float* __restrict__ Wh,
              const int* __restrict__ lengths,
              float* __restrict__ out)
{
    __shared__ uint4 lw[KL / 8][NG];               // 128 KB
    __shared__ float zs[NG];                       // 4 KB
    __shared__ __align__(16) _Float16 hs_h[NH];    // 512 B

    const int b   = blockIdx.x;
    const int tid = threadIdx.x;
    const int j0  = tid;
    const int j1  = tid + 512;

    // ---- one-time LDS staging (coalesced over j at fixed k) ----
#pragma unroll
    for (int r = 0; r < KL / 8; ++r) {
        const int k = 8 * r;
        uint4 p;
        p.x = packf16(Wh[(size_t)(k + 0) * NG + j0], Wh[(size_t)(k + 1) * NG + j0]);
        p.y = packf16(Wh[(size_t)(k + 2) * NG + j0], Wh[(size_t)(k + 3) * NG + j0]);
        p.z = packf16(Wh[(size_t)(k + 4) * NG + j0], Wh[(size_t)(k + 5) * NG + j0]);
        p.w = packf16(Wh[(size_t)(k + 6) * NG + j0], Wh[(size_t)(k + 7) * NG + j0]);
        lw[r][j0] = p;
        p.x = packf16(Wh[(size_t)(k + 0) * NG + j1], Wh[(size_t)(k + 1) * NG + j1]);
        p.y = packf16(Wh[(size_t)(k + 2) * NG + j1], Wh[(size_t)(k + 3) * NG + j1]);
        p.z = packf16(Wh[(size_t)(k + 4) * NG + j1], Wh[(size_t)(k + 5) * NG + j1]);
        p.w = packf16(Wh[(size_t)(k + 6) * NG + j1], Wh[(size_t)(k + 7) * NG + j1]);
        lw[r][j1] = p;
    }

    // ---- register-resident weights, pinned against remat ----
    uint32_t wa[NQ], wb[NQ];
#pragma unroll
    for (int q = 0; q < NQ; ++q) {
        const int k = KL + 2 * q;
        uint32_t va = packf16(Wh[(size_t)k * NG + j0], Wh[(size_t)(k + 1) * NG + j0]);
        uint32_t vb = packf16(Wh[(size_t)k * NG + j1], Wh[(size_t)(k + 1) * NG + j1]);
        asm volatile("" : "+v"(va));               // opaque def: no remat
        asm volatile("" : "+v"(vb));
        wa[q] = va;
        wb[q] = vb;
    }

    if (tid < NH) hs_h[tid] = (_Float16)0.0f;
    float c = 0.0f, hlast = 0.0f;
    __syncthreads();

    const int len   = lengths[b];
    const int steps = (len < 1) ? 1 : len;         // idx = max(0,len-1) -> idx+1 steps

    for (int t = 0; t < steps; ++t) {
        // issue early; consumed only at zs write (dot work hides L3/HBM latency)
        const float zx0 = ZX[((size_t)b * NT + t) * NG + j0];
        const float zx1 = ZX[((size_t)b * NT + t) * NG + j1];

        float a0 = 0.0f, a1 = 0.0f;    // col j0
        float b0 = 0.0f, b1 = 0.0f;    // col j1

        // k = 0..KL-1: weights from LDS (16B lane stride = free 2-way)
#pragma unroll
        for (int r = 0; r < KL / 8; ++r) {
            const uint4 h4 = *(const uint4*)(hs_h + 8 * r);   // broadcast
            const uint4 pa = lw[r][j0];
            const uint4 pb = lw[r][j1];
            a0 = dot2(h4.x, pa.x, a0); a1 = dot2(h4.y, pa.y, a1);
            a0 = dot2(h4.z, pa.z, a0); a1 = dot2(h4.w, pa.w, a1);
            b0 = dot2(h4.x, pb.x, b0); b1 = dot2(h4.y, pb.y, b1);
            b0 = dot2(h4.z, pb.z, b0); b1 = dot2(h4.w, pb.w, b1);
        }

        // k = KL..255: register-resident weights
#pragma unroll
        for (int m = 0; m < NQ / 4; ++m) {
            const uint4 h4 = *(const uint4*)(hs_h + KL + 8 * m);  // broadcast
            a0 = dot2(h4.x, wa[4 * m + 0], a0);
            a1 = dot2(h4.y, wa[4 * m + 1], a1);
            a0 = dot2(h4.z, wa[4 * m + 2], a0);
            a1 = dot2(h4.w, wa[4 * m + 3], a1);
            b0 = dot2(h4.x, wb[4 * m + 0], b0);
            b1 = dot2(h4.y, wb[4 * m + 1], b1);
            b0 = dot2(h4.z, wb[4 * m + 2], b0);
            b1 = dot2(h4.w, wb[4 * m + 3], b1);
        }

        zs[j0] = zx0 + a0 + a1;
        zs[j1] = zx1 + b0 + b1;
        __syncthreads();                            // zs complete

        if (tid < NH) {                             // waves 0-3 (wave-uniform)
            const float iv = zs[tid];
            const float fv = zs[NH + tid];
            const float gv = zs[2 * NH + tid];
            const float ov = zs[3 * NH + tid];
            c = sigf(fv) * c + sigf(iv) * tanh_fast(gv);
            hlast = sigf(ov) * tanh_fast(c);
            hs_h[tid] = (_Float16)hlast;
        }
        __syncthreads();                            // new h visible
    }

    if (tid < NH) out[(size_t)b * NH + tid] = hlast;
}

// ---------------------------------------------------------------------------
// Fallback recurrence (streams weights; used only if ws can't hold ZX)
__global__ __launch_bounds__(512) void rec_fallback(
    const float* __restrict__ X,
    const float* __restrict__ Wi,
    const float* __restrict__ Wh,
    const float* __restrict__ bias,
    const int* __restrict__ lengths,
    float* __restrict__ out)
{
    __shared__ float hs[NH];
    __shared__ float zs[NG];
    __shared__ float xs[ND];

    const int b   = blockIdx.x;
    const int tid = threadIdx.x;
    const int c0  = tid * 2;

    const int len   = lengths[b];
    const int steps = (len < 1) ? 1 : len;

    float c_state = 0.0f;
    if (tid < NH) hs[tid] = 0.0f;
    const float b0 = bias[c0], b1 = bias[c0 + 1];
    __syncthreads();

    for (int t = 0; t < steps; ++t) {
        float a0 = b0, a1 = b1;
        if (tid < ND) xs[tid] = X[((size_t)b * NT + t) * ND + tid];
        __syncthreads();
#pragma unroll 2
        for (int k = 0; k < ND; k += 4) {
            const float4 xv = *(const float4*)(xs + k);
            const float2 w0 = *(const float2*)(Wi + (size_t)(k + 0) * NG + c0);
            const float2 w1 = *(const float2*)(Wi + (size_t)(k + 1) * NG + c0);
            const float2 w2 = *(const float2*)(Wi + (size_t)(k + 2) * NG + c0);
            const float2 w3 = *(const float2*)(Wi + (size_t)(k + 3) * NG + c0);
            a0 = fmaf(xv.x, w0.x, a0); a1 = fmaf(xv.x, w0.y, a1);
            a0 = fmaf(xv.y, w1.x, a0); a1 = fmaf(xv.y, w1.y, a1);
            a0 = fmaf(xv.z, w2.x, a0); a1 = fmaf(xv.z, w2.y, a1);
            a0 = fmaf(xv.w, w3.x, a0); a1 = fmaf(xv.w, w3.y, a1);
        }
#pragma unroll 2
        for (int k = 0; k < NH; k += 4) {
            const float4 hv = *(const float4*)(hs + k);
            const float2 w0 = *(const float2*)(Wh + (size_t)(k + 0) * NG + c0);
            const float2 w1 = *(const float2*)(Wh + (size_t)(k + 1) * NG + c0);
            const float2 w2 = *(const float2*)(Wh + (size_t)(k + 2) * NG + c0);
            const float2 w3 = *(const float2*)(Wh + (size_t)(k + 3) * NG + c0);
            a0 = fmaf(hv.x, w0.x, a0); a1 = fmaf(hv.x, w0.y, a1);
            a0 = fmaf(hv.y, w1.x, a0); a1 = fmaf(hv.y, w1.y, a1);
            a0 = fmaf(hv.z, w2.x, a0); a1 = fmaf(hv.z, w2.y, a1);
            a0 = fmaf(hv.w, w3.x, a0); a1 = fmaf(hv.w, w3.y, a1);
        }

        float2 zo2; zo2.x = a0; zo2.y = a1;
        *(float2*)(zs + c0) = zo2;
        __syncthreads();

        if (tid < NH) {
            const float iv = zs[tid];
            const float fv = zs[NH + tid];
            const float gv = zs[2 * NH + tid];
            const float ov = zs[3 * NH + tid];
            c_state = sigf(fv) * c_state + sigf(iv) * tanh_fast(gv);
            hs[tid] = sigf(ov) * tanh_fast(c_state);
        }
        __syncthreads();
    }

    if (tid < NH) out[(size_t)b * NH + tid] = hs[tid];
}

extern "C" void kernel_launch(void* const* d_in, const int* in_sizes, int n_in,
                              void* d_out, int out_size, void* d_ws, size_t ws_size,
                              hipStream_t stream) {
    const float* X       = (const float*)d_in[0];
    const int*   lengths = (const int*)d_in[1];
    const float* Wi      = (const float*)d_in[2];
    const float* Wh      = (const float*)d_in[3];
    const float* bias    = (const float*)d_in[4];
    float* out = (float*)d_out;

    const size_t zx_bytes = (size_t)NB * NT * NG * sizeof(float);  // 256 MB
    float* ZX = (float*)d_ws;

    if (ws_size >= zx_bytes) {
        zx_mfma<<<dim3((NB * NT) / 64, NG / 256), dim3(256), 0, stream>>>(X, Wi, bias, ZX);
        rec_pers<<<dim3(NB), dim3(TPB), 0, stream>>>(ZX, Wh, lengths, out);
    } else {
        rec_fallback<<<dim3(NB), dim3(512), 0, stream>>>(X, Wi, Wh, bias, lengths, out);
    }
}